// Round 3
// baseline (491.601 us; speedup 1.0000x reference)
//
#include <hip/hip_runtime.h>
#include <hip/hip_bf16.h>

// Problem constants
// x:      (2, 32, 32, 480)  NCHW fp32
// qkv_w:  (96, 32, 3, 3)
// qkv_b:  (96,)
// out_w:  (32, 32, 3, 3)
// D_MODEL=32, N_HEADS=8, dh=4, QUERY_SHAPE=24, MEM_FLANGE=8
// H=32, W=480, nb=20 blocks, wlen=40, keys per block = 32*40=1280,
// queries per block = 32*24 = 768.

#define HW 15360            // 32*480 (one channel plane)
#define CH_STRIDE 15360

// ---------------------------------------------------------------------------
// Generic 3x3 conv, padding 1, NCHW. One thread per output pixel.
// blockIdx.y = b*Cout + co (weights uniform per block -> scalar loads)
// blockIdx.x covers 32*480/256 = 60 chunks of pixels.
// ---------------------------------------------------------------------------
__global__ __launch_bounds__(256) void conv3x3_kernel(
    const float* __restrict__ in, const float* __restrict__ wgt,
    const float* __restrict__ bias, float* __restrict__ out,
    int Cin, int Cout)
{
    int bc  = blockIdx.y;            // b*Cout + co
    int co  = bc % Cout;
    int b   = bc / Cout;
    int pix = blockIdx.x * 256 + threadIdx.x;   // < 15360
    int y   = pix / 480;
    int w   = pix - y * 480;

    const float* wbase = wgt + (size_t)co * Cin * 9;
    const float* ibase = in + (size_t)b * Cin * HW;

    float acc = bias ? bias[co] : 0.0f;

    for (int ci = 0; ci < Cin; ++ci) {
        const float* iplane = ibase + (size_t)ci * HW;
        const float* wk = wbase + ci * 9;
#pragma unroll
        for (int dy = 0; dy < 3; ++dy) {
            int yy = y + dy - 1;
            if (yy < 0 || yy >= 32) continue;
            const float* r = iplane + yy * 480;
            float w0 = wk[dy * 3 + 0];
            float w1 = wk[dy * 3 + 1];
            float w2 = wk[dy * 3 + 2];
            if (w > 0)   acc += w0 * r[w - 1];
            acc += w1 * r[w];
            if (w < 479) acc += w2 * r[w + 1];
        }
    }
    out[(size_t)bc * HW + pix] = acc;
}

// ---------------------------------------------------------------------------
// Blocked local attention.
// One workgroup per (b, head, blk): 2*8*20 = 320 workgroups, 256 threads.
// Each thread owns 3 queries (768/256). K/V window staged in LDS as float4.
// Single-pass softmax without max subtraction (logits are O(1), safe in fp32).
// ---------------------------------------------------------------------------
__global__ __launch_bounds__(256) void attn_kernel(
    const float* __restrict__ qkv, float* __restrict__ att)
{
    __shared__ float4 ks[1280];
    __shared__ float4 vs[1280];

    int bid = blockIdx.x;
    int blk = bid % 20;
    int h   = (bid / 20) % 8;
    int b   = bid / 160;
    int tid = threadIdx.x;

    // base of this (b, head) group's channels: channel = h*12 + j
    const float* base = qkv + (size_t)(b * 96 + h * 12) * CH_STRIDE;
    const float* kbase = base + 4 * CH_STRIDE;
    const float* vbase = base + 8 * CH_STRIDE;

    // stage K/V window: j = y*40 + wc, padded W position = blk*24 + wc - 8
    for (int j = tid; j < 1280; j += 256) {
        int y  = j / 40;
        int wc = j - y * 40;
        int wpos = blk * 24 + wc - 8;
        float4 kv = make_float4(0.f, 0.f, 0.f, 0.f);
        float4 vv = make_float4(0.f, 0.f, 0.f, 0.f);
        if ((unsigned)wpos < 480u) {
            int off = y * 480 + wpos;
            kv.x = kbase[off];
            kv.y = kbase[off + CH_STRIDE];
            kv.z = kbase[off + 2 * CH_STRIDE];
            kv.w = kbase[off + 3 * CH_STRIDE];
            vv.x = vbase[off];
            vv.y = vbase[off + CH_STRIDE];
            vv.z = vbase[off + 2 * CH_STRIDE];
            vv.w = vbase[off + 3 * CH_STRIDE];
        }
        ks[j] = kv;
        vs[j] = vv;
    }

    // load queries: i = tid + 256*r, i = y*24 + qc
    float q0[3], q1[3], q2[3], q3[3];
#pragma unroll
    for (int r = 0; r < 3; ++r) {
        int i  = tid + 256 * r;
        int y  = i / 24;
        int qc = i - y * 24;
        int off = y * 480 + blk * 24 + qc;
        q0[r] = base[off] * 0.5f;
        q1[r] = base[off + CH_STRIDE] * 0.5f;
        q2[r] = base[off + 2 * CH_STRIDE] * 0.5f;
        q3[r] = base[off + 3 * CH_STRIDE] * 0.5f;
    }

    __syncthreads();

    float l[3]  = {0.f, 0.f, 0.f};
    float ax[3] = {0.f, 0.f, 0.f};
    float ay[3] = {0.f, 0.f, 0.f};
    float az[3] = {0.f, 0.f, 0.f};
    float aw[3] = {0.f, 0.f, 0.f};

#pragma unroll 4
    for (int j = 0; j < 1280; ++j) {
        float4 k4 = ks[j];
        float4 v4 = vs[j];
#pragma unroll
        for (int r = 0; r < 3; ++r) {
            float s = q0[r] * k4.x + q1[r] * k4.y + q2[r] * k4.z + q3[r] * k4.w;
            float e = __expf(s);
            l[r]  += e;
            ax[r] += e * v4.x;
            ay[r] += e * v4.y;
            az[r] += e * v4.z;
            aw[r] += e * v4.w;
        }
    }

    // write output: channel = h*4 + d, W = blk*24 + qc
#pragma unroll
    for (int r = 0; r < 3; ++r) {
        int i  = tid + 256 * r;
        int y  = i / 24;
        int qc = i - y * 24;
        float inv = 1.0f / l[r];
        float* o = att + (size_t)((b * 32 + h * 4) * 32 + y) * 480 + blk * 24 + qc;
        o[0]             = ax[r] * inv;
        o[CH_STRIDE]     = ay[r] * inv;
        o[2 * CH_STRIDE] = az[r] * inv;
        o[3 * CH_STRIDE] = aw[r] * inv;
    }
}

extern "C" void kernel_launch(void* const* d_in, const int* in_sizes, int n_in,
                              void* d_out, int out_size, void* d_ws, size_t ws_size,
                              hipStream_t stream) {
    const float* x     = (const float*)d_in[0];
    const float* qkv_w = (const float*)d_in[1];
    const float* qkv_b = (const float*)d_in[2];
    const float* out_w = (const float*)d_in[3];
    float* out = (float*)d_out;

    float* qkv = (float*)d_ws;                       // 2*96*32*480 = 2,949,120 floats
    float* att = qkv + (size_t)2 * 96 * HW;          //   983,040 floats

    // conv1: x (2,32,32,480) -> qkv (2,96,32,480), 3x3 pad 1, + bias
    conv3x3_kernel<<<dim3(60, 192), 256, 0, stream>>>(x, qkv_w, qkv_b, qkv, 32, 96);

    // attention: qkv -> att (2,32,32,480)
    attn_kernel<<<320, 256, 0, stream>>>(qkv, att);

    // conv2: att -> out (2,32,32,480), 3x3 pad 1, no bias
    conv3x3_kernel<<<dim3(60, 64), 256, 0, stream>>>(att, out_w, nullptr, out, 32, 32);
}

// Round 8
// 198.327 us; speedup vs baseline: 2.4787x; 2.4787x over previous
//
#include <hip/hip_runtime.h>
#include <hip/hip_bf16.h>

// x:      (2, 32, 32, 480)  NCHW fp32
// qkv_w:  (96, 32, 3, 3), qkv_b: (96,), out_w: (32, 32, 3, 3)
// D_MODEL=32, N_HEADS=8, dh=4, QUERY_SHAPE=24, MEM_FLANGE=8
// H=32, W=480, nb=20, wlen=40; per (b,h,blk): 768 queries x 1280 keys.

#define HW 15360   // 32*480, one channel plane

// ---------------------------------------------------------------------------
// Repack weights [Cout][32][3][3] -> [32*9][Cout] so that a float4 read gives
// 4 consecutive output channels' weights for one (ci, ky, kx).
// ---------------------------------------------------------------------------
__global__ __launch_bounds__(256) void repack_w(const float* __restrict__ w,
                                                float* __restrict__ wt, int Cout) {
    int i = blockIdx.x * 256 + threadIdx.x;
    int n = Cout * 288;
    if (i >= n) return;
    int co = i / 288;
    int r  = i - co * 288;            // ci*9 + k
    wt[r * Cout + co] = w[i];
}

// ---------------------------------------------------------------------------
// 3x3 conv, pad 1, NCHW, Cin=32. Each thread: 1 pixel x CO_TILE out-channels.
// Weights read from repacked wt as uniform float4 (L1 broadcast / s_load).
// Bounds via precomputed clamped offsets + mask multiplies (no divergence).
// ---------------------------------------------------------------------------
template<int CO_TILE>
__global__ __launch_bounds__(256) void conv3x3_tiled(
    const float* __restrict__ in, const float* __restrict__ wt,
    const float* __restrict__ bias, float* __restrict__ out, int Cout)
{
    int nct = Cout / CO_TILE;
    int bc  = blockIdx.y;
    int ct  = bc % nct;
    int b   = bc / nct;
    int co0 = ct * CO_TILE;
    int pix = blockIdx.x * 256 + threadIdx.x;   // < 15360
    int y   = pix / 480;
    int w   = pix - y * 480;

    const float* ibase = in + (size_t)b * 32 * HW + y * 480 + w;

    bool ym = y > 0, yp = y < 31, wm = w > 0, wp = w < 479;
    int   off[9];
    float msk[9];
    {
        const bool c[9] = { ym && wm, ym, ym && wp,
                            wm,       true, wp,
                            yp && wm, yp, yp && wp };
        const int  o[9] = { -481, -480, -479, -1, 0, 1, 479, 480, 481 };
#pragma unroll
        for (int k = 0; k < 9; ++k) {
            off[k] = c[k] ? o[k] : 0;
            msk[k] = c[k] ? 1.f : 0.f;
        }
    }

    float acc[CO_TILE];
#pragma unroll
    for (int i = 0; i < CO_TILE; ++i) acc[i] = bias ? bias[co0 + i] : 0.f;

    for (int ci = 0; ci < 32; ++ci) {
        const float* ip = ibase + ci * HW;
        float v[9];
#pragma unroll
        for (int k = 0; k < 9; ++k) v[k] = ip[off[k]] * msk[k];

        const float* wrow = wt + ci * 9 * Cout + co0;
#pragma unroll
        for (int k = 0; k < 9; ++k) {
            float xv = v[k];
            const float4* w4p = (const float4*)(wrow + k * Cout);
#pragma unroll
            for (int c = 0; c < CO_TILE / 4; ++c) {
                float4 ww = w4p[c];
                acc[c * 4 + 0] += xv * ww.x;
                acc[c * 4 + 1] += xv * ww.y;
                acc[c * 4 + 2] += xv * ww.z;
                acc[c * 4 + 3] += xv * ww.w;
            }
        }
    }

    size_t obase = (size_t)(b * Cout + co0) * HW + pix;
#pragma unroll
    for (int i = 0; i < CO_TILE; ++i) out[obase + (size_t)i * HW] = acc[i];
}

// ---------------------------------------------------------------------------
// Blocked local attention. One WG per (b, head, blk, third): 960 WGs,
// 256 threads, 1 query/thread. K/V window (1280 x dh=4) staged in LDS.
// Single-pass softmax without max subtraction (logits O(1), exact in fp32).
// ---------------------------------------------------------------------------
__global__ __launch_bounds__(256) void attn_kernel(
    const float* __restrict__ qkv, float* __restrict__ att)
{
    __shared__ float4 ks[1280];
    __shared__ float4 vs[1280];

    int bid   = blockIdx.x;
    int third = bid % 3;
    int blk   = (bid / 3) % 20;
    int h     = (bid / 60) % 8;
    int b     = bid / 480;
    int tid   = threadIdx.x;

    const float* base  = qkv + (size_t)(b * 96 + h * 12) * HW;
    const float* kbase = base + 4 * HW;
    const float* vbase = base + 8 * HW;

    // stage K/V window: j = yy*40 + wc, padded W pos = blk*24 + wc - 8
    for (int j = tid; j < 1280; j += 256) {
        int yy   = j / 40;
        int wc   = j - yy * 40;
        int wpos = blk * 24 + wc - 8;
        float4 kv = make_float4(0.f, 0.f, 0.f, 0.f);
        float4 vv = make_float4(0.f, 0.f, 0.f, 0.f);
        if ((unsigned)wpos < 480u) {
            int o = yy * 480 + wpos;
            kv = make_float4(kbase[o], kbase[o + HW], kbase[o + 2 * HW], kbase[o + 3 * HW]);
            vv = make_float4(vbase[o], vbase[o + HW], vbase[o + 2 * HW], vbase[o + 3 * HW]);
        }
        ks[j] = kv;
        vs[j] = vv;
    }

    int qi = third * 256 + tid;       // 0..767
    int y  = qi / 24;
    int qc = qi - y * 24;
    int qo = y * 480 + blk * 24 + qc;
    float q0 = base[qo] * 0.5f;
    float q1 = base[qo + HW] * 0.5f;
    float q2 = base[qo + 2 * HW] * 0.5f;
    float q3 = base[qo + 3 * HW] * 0.5f;

    __syncthreads();

    float l = 0.f, ax = 0.f, ay = 0.f, az = 0.f, aw = 0.f;
#pragma unroll 8
    for (int j = 0; j < 1280; ++j) {
        float4 k4 = ks[j];
        float4 v4 = vs[j];
        float s = q0 * k4.x + q1 * k4.y + q2 * k4.z + q3 * k4.w;
        float e = __expf(s);
        l  += e;
        ax += e * v4.x;
        ay += e * v4.y;
        az += e * v4.z;
        aw += e * v4.w;
    }

    float inv = 1.f / l;
    float* o = att + (size_t)((b * 32 + h * 4) * 32 + y) * 480 + blk * 24 + qc;
    o[0]        = ax * inv;
    o[HW]       = ay * inv;
    o[2 * HW]   = az * inv;
    o[3 * HW]   = aw * inv;
}

extern "C" void kernel_launch(void* const* d_in, const int* in_sizes, int n_in,
                              void* d_out, int out_size, void* d_ws, size_t ws_size,
                              hipStream_t stream) {
    const float* x     = (const float*)d_in[0];
    const float* qkv_w = (const float*)d_in[1];
    const float* qkv_b = (const float*)d_in[2];
    const float* out_w = (const float*)d_in[3];
    float* out = (float*)d_out;

    float* wt1 = (float*)d_ws;                         // 32*9*96  = 27648 floats
    float* wt2 = wt1 + 32 * 9 * 96;                    // 32*9*32  = 9216 floats
    float* qkv = wt2 + 32 * 9 * 32;                    // 2*96*HW  = 2,949,120 floats
    float* att = qkv + (size_t)2 * 96 * HW;            // 2*32*HW  = 983,040 floats

    // repack weights for coalesced-by-co float4 reads
    repack_w<<<(96 * 288 + 255) / 256, 256, 0, stream>>>(qkv_w, wt1, 96);
    repack_w<<<(32 * 288 + 255) / 256, 256, 0, stream>>>(out_w, wt2, 32);

    // conv1: x -> qkv (2,96,32,480); 16 co per thread
    conv3x3_tiled<16><<<dim3(60, 2 * 6), 256, 0, stream>>>(x, wt1, qkv_b, qkv, 96);

    // attention: qkv -> att (2,32,32,480)
    attn_kernel<<<960, 256, 0, stream>>>(qkv, att);

    // conv2: att -> out; 8 co per thread
    conv3x3_tiled<8><<<dim3(60, 2 * 4), 256, 0, stream>>>(att, wt2, nullptr, out, 32);
}

// Round 9
// 166.989 us; speedup vs baseline: 2.9439x; 1.1877x over previous
//
#include <hip/hip_runtime.h>
#include <hip/hip_bf16.h>

// x:      (2, 32, 32, 480)  NCHW fp32
// qkv_w:  (96, 32, 3, 3), qkv_b: (96,), out_w: (32, 32, 3, 3)
// D_MODEL=32, N_HEADS=8, dh=4, QUERY_SHAPE=24, MEM_FLANGE=8
// H=32, W=480, nb=20, wlen=40; per (b,h,blk): 768 queries x 1280 keys.

#define HW 15360   // 32*480, one channel plane
#define KSPLIT 4
#define KEYS_PER_SPLIT 320   // 1280 / 4

// ---------------------------------------------------------------------------
// Repack weights [Cout][32][3][3] -> [32*9][Cout].
// ---------------------------------------------------------------------------
__global__ __launch_bounds__(256) void repack_w(const float* __restrict__ w,
                                                float* __restrict__ wt, int Cout) {
    int i = blockIdx.x * 256 + threadIdx.x;
    int n = Cout * 288;
    if (i >= n) return;
    int co = i / 288;
    int r  = i - co * 288;            // ci*9 + k
    wt[r * Cout + co] = w[i];
}

// ---------------------------------------------------------------------------
// 3x3 conv, pad 1, NCHW, Cin=32. Each thread: 1 pixel x CO_TILE out-channels.
// ---------------------------------------------------------------------------
template<int CO_TILE>
__global__ __launch_bounds__(256) void conv3x3_tiled(
    const float* __restrict__ in, const float* __restrict__ wt,
    const float* __restrict__ bias, float* __restrict__ out, int Cout)
{
    int nct = Cout / CO_TILE;
    int bc  = blockIdx.y;
    int ct  = bc % nct;
    int b   = bc / nct;
    int co0 = ct * CO_TILE;
    int pix = blockIdx.x * 256 + threadIdx.x;   // < 15360
    int y   = pix / 480;
    int w   = pix - y * 480;

    const float* ibase = in + (size_t)b * 32 * HW + y * 480 + w;

    bool ym = y > 0, yp = y < 31, wm = w > 0, wp = w < 479;
    int   off[9];
    float msk[9];
    {
        const bool c[9] = { ym && wm, ym, ym && wp,
                            wm,       true, wp,
                            yp && wm, yp, yp && wp };
        const int  o[9] = { -481, -480, -479, -1, 0, 1, 479, 480, 481 };
#pragma unroll
        for (int k = 0; k < 9; ++k) {
            off[k] = c[k] ? o[k] : 0;
            msk[k] = c[k] ? 1.f : 0.f;
        }
    }

    float acc[CO_TILE];
#pragma unroll
    for (int i = 0; i < CO_TILE; ++i) acc[i] = bias ? bias[co0 + i] : 0.f;

    for (int ci = 0; ci < 32; ++ci) {
        const float* ip = ibase + ci * HW;
        float v[9];
#pragma unroll
        for (int k = 0; k < 9; ++k) v[k] = ip[off[k]] * msk[k];

        const float* wrow = wt + ci * 9 * Cout + co0;
#pragma unroll
        for (int k = 0; k < 9; ++k) {
            float xv = v[k];
            const float4* w4p = (const float4*)(wrow + k * Cout);
#pragma unroll
            for (int c = 0; c < CO_TILE / 4; ++c) {
                float4 ww = w4p[c];
                acc[c * 4 + 0] += xv * ww.x;
                acc[c * 4 + 1] += xv * ww.y;
                acc[c * 4 + 2] += xv * ww.z;
                acc[c * 4 + 3] += xv * ww.w;
            }
        }
    }

    size_t obase = (size_t)(b * Cout + co0) * HW + pix;
#pragma unroll
    for (int i = 0; i < CO_TILE; ++i) out[obase + (size_t)i * HW] = acc[i];
}

// ---------------------------------------------------------------------------
// Attention, pass 1: partial softmax-weighted sums over a key sub-range.
// WG = (b, h, blk, ks): 320*4 = 1280 WGs, 256 threads, 3 queries/thread,
// 320 keys staged in LDS (10 KB). Q pre-scaled by 0.5*log2(e); exp via
// native v_exp (exp2). Writes per-query partials (l, a0..a3) to ws.
// ---------------------------------------------------------------------------
__global__ __launch_bounds__(256) void attn_part(
    const float* __restrict__ qkv, float* __restrict__ part)
{
    __shared__ float4 ks_s[KEYS_PER_SPLIT];
    __shared__ float4 vs_s[KEYS_PER_SPLIT];

    int wg    = blockIdx.x;
    int ks    = wg & 3;
    int bhblk = wg >> 2;
    int blk   = bhblk % 20;
    int h     = (bhblk / 20) % 8;
    int b     = bhblk / 160;
    int tid   = threadIdx.x;

    const float* base  = qkv + (size_t)(b * 96 + h * 12) * HW;
    const float* kbase = base + 4 * HW;
    const float* vbase = base + 8 * HW;

    // stage this split's K/V slice: global key j = ks*320 + jj, j = yy*40+wc
    for (int jj = tid; jj < KEYS_PER_SPLIT; jj += 256) {
        int j    = ks * KEYS_PER_SPLIT + jj;
        int yy   = j / 40;
        int wc   = j - yy * 40;
        int wpos = blk * 24 + wc - 8;
        float4 kv = make_float4(0.f, 0.f, 0.f, 0.f);
        float4 vv = make_float4(0.f, 0.f, 0.f, 0.f);
        if ((unsigned)wpos < 480u) {
            int o = yy * 480 + wpos;
            kv = make_float4(kbase[o], kbase[o + HW], kbase[o + 2 * HW], kbase[o + 3 * HW]);
            vv = make_float4(vbase[o], vbase[o + HW], vbase[o + 2 * HW], vbase[o + 3 * HW]);
        }
        ks_s[jj] = kv;
        vs_s[jj] = vv;
    }

    // load 3 queries, pre-scaled by 0.5 * log2(e) so softmax uses 2^s
    const float QSCALE = 0.5f * 1.44269504f;
    float q0[3], q1[3], q2[3], q3[3];
#pragma unroll
    for (int r = 0; r < 3; ++r) {
        int qi = tid + 256 * r;          // 0..767
        int y  = qi / 24;
        int qc = qi - y * 24;
        int qo = y * 480 + blk * 24 + qc;
        q0[r] = base[qo] * QSCALE;
        q1[r] = base[qo + HW] * QSCALE;
        q2[r] = base[qo + 2 * HW] * QSCALE;
        q3[r] = base[qo + 3 * HW] * QSCALE;
    }

    __syncthreads();

    float l[3]  = {0.f, 0.f, 0.f};
    float a0[3] = {0.f, 0.f, 0.f};
    float a1[3] = {0.f, 0.f, 0.f};
    float a2[3] = {0.f, 0.f, 0.f};
    float a3[3] = {0.f, 0.f, 0.f};

#pragma unroll 4
    for (int jj = 0; jj < KEYS_PER_SPLIT; ++jj) {
        float4 k4 = ks_s[jj];
        float4 v4 = vs_s[jj];
#pragma unroll
        for (int r = 0; r < 3; ++r) {
            float s = q0[r] * k4.x + q1[r] * k4.y + q2[r] * k4.z + q3[r] * k4.w;
            float e = __builtin_amdgcn_exp2f(s);
            l[r]  += e;
            a0[r] += e * v4.x;
            a1[r] += e * v4.y;
            a2[r] += e * v4.z;
            a3[r] += e * v4.w;
        }
    }

    // partials layout: part[((wg)*5 + c)*768 + q]
    float* p = part + (size_t)wg * 5 * 768;
#pragma unroll
    for (int r = 0; r < 3; ++r) {
        int qi = tid + 256 * r;
        p[qi]            = l[r];
        p[768 + qi]      = a0[r];
        p[2 * 768 + qi]  = a1[r];
        p[3 * 768 + qi]  = a2[r];
        p[4 * 768 + qi]  = a3[r];
    }
}

// ---------------------------------------------------------------------------
// Attention, pass 2: combine KSPLIT partials, normalize, write att (NCHW).
// 960 WGs x 256 threads = 245,760 = one thread per (bhblk, q).
// ---------------------------------------------------------------------------
__global__ __launch_bounds__(256) void attn_combine(
    const float* __restrict__ part, float* __restrict__ att)
{
    int qglob = blockIdx.x * 256 + threadIdx.x;   // < 320*768
    int bhblk = qglob / 768;
    int q     = qglob - bhblk * 768;
    int blk   = bhblk % 20;
    int h     = (bhblk / 20) % 8;
    int b     = bhblk / 160;

    float l = 0.f, a0 = 0.f, a1 = 0.f, a2 = 0.f, a3 = 0.f;
#pragma unroll
    for (int ks = 0; ks < KSPLIT; ++ks) {
        const float* p = part + (size_t)(bhblk * 4 + ks) * 5 * 768 + q;
        l  += p[0];
        a0 += p[768];
        a1 += p[2 * 768];
        a2 += p[3 * 768];
        a3 += p[4 * 768];
    }

    float inv = 1.f / l;
    int y  = q / 24;
    int qc = q - y * 24;
    float* o = att + (size_t)((b * 32 + h * 4) * 32 + y) * 480 + blk * 24 + qc;
    o[0]      = a0 * inv;
    o[HW]     = a1 * inv;
    o[2 * HW] = a2 * inv;
    o[3 * HW] = a3 * inv;
}

extern "C" void kernel_launch(void* const* d_in, const int* in_sizes, int n_in,
                              void* d_out, int out_size, void* d_ws, size_t ws_size,
                              hipStream_t stream) {
    const float* x     = (const float*)d_in[0];
    const float* qkv_w = (const float*)d_in[1];
    const float* qkv_b = (const float*)d_in[2];
    const float* out_w = (const float*)d_in[3];
    float* out = (float*)d_out;

    float* wt1  = (float*)d_ws;                        // 32*9*96  = 27,648 fl
    float* wt2  = wt1 + 32 * 9 * 96;                   // 32*9*32  = 9,216 fl
    float* qkv  = wt2 + 32 * 9 * 32;                   // 2*96*HW  = 2,949,120 fl
    float* att  = qkv + (size_t)2 * 96 * HW;           // 2*32*HW  = 983,040 fl
    float* part = att + (size_t)2 * 32 * HW;           // 1280*5*768 = 4,915,200 fl (~19.7 MB)

    // repack weights for coalesced-by-co float4 reads
    repack_w<<<(96 * 288 + 255) / 256, 256, 0, stream>>>(qkv_w, wt1, 96);
    repack_w<<<(32 * 288 + 255) / 256, 256, 0, stream>>>(out_w, wt2, 32);

    // conv1: x -> qkv (2,96,32,480); 16 co per thread
    conv3x3_tiled<16><<<dim3(60, 2 * 6), 256, 0, stream>>>(x, wt1, qkv_b, qkv, 96);

    // attention pass 1: partials over key splits
    attn_part<<<1280, 256, 0, stream>>>(qkv, part);

    // attention pass 2: combine + normalize -> att (2,32,32,480)
    attn_combine<<<960, 256, 0, stream>>>(part, att);

    // conv2: att -> out; 8 co per thread
    conv3x3_tiled<8><<<dim3(60, 2 * 4), 256, 0, stream>>>(att, wt2, nullptr, out, 32);
}

// Round 10
// 125.499 us; speedup vs baseline: 3.9172x; 1.3306x over previous
//
#include <hip/hip_runtime.h>
#include <hip/hip_bf16.h>

// x:      (2, 32, 32, 480)  NCHW fp32
// qkv_w:  (96, 32, 3, 3), qkv_b: (96,), out_w: (32, 32, 3, 3)
// D_MODEL=32, N_HEADS=8, dh=4, QUERY_SHAPE=24, MEM_FLANGE=8
// H=32, W=480, nb=20, wlen=40; per (b,h,blk): 768 queries x 1280 keys.

#define HW 15360   // 32*480, one channel plane

typedef _Float16 half4 __attribute__((ext_vector_type(4)));
typedef float floatx4 __attribute__((ext_vector_type(4)));

// ---------------------------------------------------------------------------
// Repack weights [Cout][32][3][3] -> [32*9][Cout].
// ---------------------------------------------------------------------------
__global__ __launch_bounds__(256) void repack_w(const float* __restrict__ w,
                                                float* __restrict__ wt, int Cout) {
    int i = blockIdx.x * 256 + threadIdx.x;
    int n = Cout * 288;
    if (i >= n) return;
    int co = i / 288;
    int r  = i - co * 288;            // ci*9 + k
    wt[r * Cout + co] = w[i];
}

// ---------------------------------------------------------------------------
// 3x3 conv, pad 1, NCHW, Cin=32. Each thread: 1 pixel x CO_TILE out-channels.
// ---------------------------------------------------------------------------
template<int CO_TILE>
__global__ __launch_bounds__(256) void conv3x3_tiled(
    const float* __restrict__ in, const float* __restrict__ wt,
    const float* __restrict__ bias, float* __restrict__ out, int Cout)
{
    int nct = Cout / CO_TILE;
    int bc  = blockIdx.y;
    int ct  = bc % nct;
    int b   = bc / nct;
    int co0 = ct * CO_TILE;
    int pix = blockIdx.x * 256 + threadIdx.x;   // < 15360
    int y   = pix / 480;
    int w   = pix - y * 480;

    const float* ibase = in + (size_t)b * 32 * HW + y * 480 + w;

    bool ym = y > 0, yp = y < 31, wm = w > 0, wp = w < 479;
    int   off[9];
    float msk[9];
    {
        const bool c[9] = { ym && wm, ym, ym && wp,
                            wm,       true, wp,
                            yp && wm, yp, yp && wp };
        const int  o[9] = { -481, -480, -479, -1, 0, 1, 479, 480, 481 };
#pragma unroll
        for (int k = 0; k < 9; ++k) {
            off[k] = c[k] ? o[k] : 0;
            msk[k] = c[k] ? 1.f : 0.f;
        }
    }

    float acc[CO_TILE];
#pragma unroll
    for (int i = 0; i < CO_TILE; ++i) acc[i] = bias ? bias[co0 + i] : 0.f;

    for (int ci = 0; ci < 32; ++ci) {
        const float* ip = ibase + ci * HW;
        float v[9];
#pragma unroll
        for (int k = 0; k < 9; ++k) v[k] = ip[off[k]] * msk[k];

        const float* wrow = wt + ci * 9 * Cout + co0;
#pragma unroll
        for (int k = 0; k < 9; ++k) {
            float xv = v[k];
            const float4* w4p = (const float4*)(wrow + k * Cout);
#pragma unroll
            for (int c = 0; c < CO_TILE / 4; ++c) {
                float4 ww = w4p[c];
                acc[c * 4 + 0] += xv * ww.x;
                acc[c * 4 + 1] += xv * ww.y;
                acc[c * 4 + 2] += xv * ww.z;
                acc[c * 4 + 3] += xv * ww.w;
            }
        }
    }

    size_t obase = (size_t)(b * Cout + co0) * HW + pix;
#pragma unroll
    for (int i = 0; i < CO_TILE; ++i) out[obase + (size_t)i * HW] = acc[i];
}

// ---------------------------------------------------------------------------
// MFMA flash attention. One WG per (b,h,blk): 320 WGs x 512 threads (8 waves).
// Each wave owns 6 q-tiles of 16 queries (8*6*16 = 768).
// Per 16-key tile: S' = K·Q^T via mfma_16x16x16_f16 (swapped operands so the
// C-frag of S' is directly the A-frag of P), exp2 in-register, P·[V|1|0] via
// second MFMA. Ones-column of V gives the softmax denominator for free.
// OOB (flange-padded) keys: K=V=0, ones=1 -> exp(0)=1 in denom, matches ref.
// ---------------------------------------------------------------------------
__global__ __launch_bounds__(512) void attn_mfma(
    const float* __restrict__ qkv, float* __restrict__ att)
{
    __shared__ _Float16 Kl[1280 * 4];   // [j][d], 8B per key -> A-frag ds_read_b64
    __shared__ _Float16 Vl[5 * 1280];   // [n][j] transposed; row 4 = ones

    int bhblk = blockIdx.x;
    int blk = bhblk % 20;
    int h   = (bhblk / 20) % 8;
    int b   = bhblk / 160;
    int tid  = threadIdx.x;
    int lane = tid & 63;
    int wv   = tid >> 6;     // 0..7

    const float* base = qkv + (size_t)(b * 96 + h * 12) * HW;
    const float* kb = base + 4 * HW;
    const float* vb = base + 8 * HW;

    // stage K (key-major f16) and V^T (+ones row) into LDS
    for (int j = tid; j < 1280; j += 512) {
        int yy = j / 40, wc = j - yy * 40;
        int wpos = blk * 24 + wc - 8;
        float k0 = 0.f, k1 = 0.f, k2 = 0.f, k3 = 0.f;
        float v0 = 0.f, v1 = 0.f, v2 = 0.f, v3 = 0.f;
        if ((unsigned)wpos < 480u) {
            int o = yy * 480 + wpos;
            k0 = kb[o]; k1 = kb[o + HW]; k2 = kb[o + 2 * HW]; k3 = kb[o + 3 * HW];
            v0 = vb[o]; v1 = vb[o + HW]; v2 = vb[o + 2 * HW]; v3 = vb[o + 3 * HW];
        }
        half4 kk = { (_Float16)k0, (_Float16)k1, (_Float16)k2, (_Float16)k3 };
        *(half4*)&Kl[j * 4] = kk;
        Vl[j]            = (_Float16)v0;
        Vl[1280 + j]     = (_Float16)v1;
        Vl[2 * 1280 + j] = (_Float16)v2;
        Vl[3 * 1280 + j] = (_Float16)v3;
        Vl[4 * 1280 + j] = (_Float16)1.0f;
    }

    // Q B-frags: lane<16 holds query (tile_base+lane)'s 4 dims (pre-scaled)
    const float QS = 0.5f * 1.44269504f;   // dh^-0.5 * log2(e)
    half4 qf[6];
#pragma unroll
    for (int t = 0; t < 6; ++t) {
        half4 qq = { (_Float16)0.f, (_Float16)0.f, (_Float16)0.f, (_Float16)0.f };
        if (lane < 16) {
            int q = wv * 96 + t * 16 + lane;
            int y = q / 24, qc = q - y * 24;
            int o = y * 480 + blk * 24 + qc;
            qq[0] = (_Float16)(base[o] * QS);
            qq[1] = (_Float16)(base[o + HW] * QS);
            qq[2] = (_Float16)(base[o + 2 * HW] * QS);
            qq[3] = (_Float16)(base[o + 3 * HW] * QS);
        }
        qf[t] = qq;
    }

    __syncthreads();

    const half4   hz = { (_Float16)0.f, (_Float16)0.f, (_Float16)0.f, (_Float16)0.f };
    const floatx4 fz = { 0.f, 0.f, 0.f, 0.f };

    floatx4 acc[6];
#pragma unroll
    for (int t = 0; t < 6; ++t) acc[t] = fz;

    int n = lane & 15;          // A-row (key) for ka; B-col (out dim) for vv
    int g = lane >> 4;
    int vn = n > 4 ? 4 : n;

    for (int kt = 0; kt < 80; ++kt) {
        int jb = kt * 16;
        // A-frag of S' = K-tile: lane holds K[jb + n][d=0..3]; lanes>=16 are d>=4 pad
        half4 ka = *(const half4*)&Kl[(jb + n) * 4];
        if (lane >= 16) ka = hz;
        // B-frag of PV = V-tile: lane holds V[jb + g*4 + i][col=n]; n==4 -> ones
        half4 vv = *(const half4*)&Vl[vn * 1280 + jb + g * 4];
        if (n > 4) vv = hz;
#pragma unroll
        for (int t = 0; t < 6; ++t) {
            floatx4 s = __builtin_amdgcn_mfma_f32_16x16x16f16(ka, qf[t], fz, 0, 0, 0);
            half4 pa;
#pragma unroll
            for (int r = 0; r < 4; ++r)
                pa[r] = (_Float16)__builtin_amdgcn_exp2f(s[r]);
            acc[t] = __builtin_amdgcn_mfma_f32_16x16x16f16(pa, vv, acc[t], 0, 0, 0);
        }
    }

    // epilogue: lane holds O[q = tile+g*4+r][n]; col 4 = softmax denominator
#pragma unroll
    for (int t = 0; t < 6; ++t) {
#pragma unroll
        for (int r = 0; r < 4; ++r) {
            float ls = __shfl(acc[t][r], (lane & 48) + 4);
            if (n < 4) {
                float val = acc[t][r] * __builtin_amdgcn_rcpf(ls);
                int q = wv * 96 + t * 16 + g * 4 + r;
                int y = q / 24, qc = q - y * 24;
                att[((size_t)(b * 32 + h * 4 + n) * 32 + y) * 480 + blk * 24 + qc] = val;
            }
        }
    }
}

extern "C" void kernel_launch(void* const* d_in, const int* in_sizes, int n_in,
                              void* d_out, int out_size, void* d_ws, size_t ws_size,
                              hipStream_t stream) {
    const float* x     = (const float*)d_in[0];
    const float* qkv_w = (const float*)d_in[1];
    const float* qkv_b = (const float*)d_in[2];
    const float* out_w = (const float*)d_in[3];
    float* out = (float*)d_out;

    float* wt1  = (float*)d_ws;                        // 32*9*96  = 27,648 fl
    float* wt2  = wt1 + 32 * 9 * 96;                   // 32*9*32  = 9,216 fl
    float* qkv  = wt2 + 32 * 9 * 32;                   // 2*96*HW  = 2,949,120 fl
    float* att  = qkv + (size_t)2 * 96 * HW;           // 2*32*HW  = 983,040 fl

    // repack weights for coalesced-by-co float4 reads
    repack_w<<<(96 * 288 + 255) / 256, 256, 0, stream>>>(qkv_w, wt1, 96);
    repack_w<<<(32 * 288 + 255) / 256, 256, 0, stream>>>(out_w, wt2, 32);

    // conv1: x -> qkv (2,96,32,480); 16 co per thread
    conv3x3_tiled<16><<<dim3(60, 2 * 6), 256, 0, stream>>>(x, wt1, qkv_b, qkv, 96);

    // attention (MFMA flash): qkv -> att (2,32,32,480)
    attn_mfma<<<320, 512, 0, stream>>>(qkv, att);

    // conv2: att -> out; 8 co per thread
    conv3x3_tiled<8><<<dim3(60, 2 * 4), 256, 0, stream>>>(att, wt2, nullptr, out, 32);
}

// Round 12
// 120.479 us; speedup vs baseline: 4.0804x; 1.0417x over previous
//
#include <hip/hip_runtime.h>
#include <hip/hip_bf16.h>

// x:      (2, 32, 32, 480)  NCHW fp32
// qkv_w:  (96, 32, 3, 3), qkv_b: (96,), out_w: (32, 32, 3, 3)
// D_MODEL=32, N_HEADS=8, dh=4, QUERY_SHAPE=24, MEM_FLANGE=8
// H=32, W=480, nb=20, wlen=40; per (b,h,blk): 768 queries x 1280 keys.

#define HW 15360   // 32*480, one channel plane
#define VSTRIDE 1300  // halves; 650 dwords = 10 mod 32 -> max 2-way bank alias

typedef _Float16 half4 __attribute__((ext_vector_type(4)));
typedef float floatx4 __attribute__((ext_vector_type(4)));

// ---------------------------------------------------------------------------
// Repack weights [Cout][32][3][3] -> [32*9][Cout].
// ---------------------------------------------------------------------------
__global__ __launch_bounds__(256) void repack_w(const float* __restrict__ w,
                                                float* __restrict__ wt, int Cout) {
    int i = blockIdx.x * 256 + threadIdx.x;
    int n = Cout * 288;
    if (i >= n) return;
    int co = i / 288;
    int r  = i - co * 288;            // ci*9 + k
    wt[r * Cout + co] = w[i];
}

// ---------------------------------------------------------------------------
// 3x3 conv, pad 1, NCHW, Cin=32. Each thread: 1 pixel x CO_TILE out-channels.
// ---------------------------------------------------------------------------
template<int CO_TILE>
__global__ __launch_bounds__(256) void conv3x3_tiled(
    const float* __restrict__ in, const float* __restrict__ wt,
    const float* __restrict__ bias, float* __restrict__ out, int Cout)
{
    int nct = Cout / CO_TILE;
    int bc  = blockIdx.y;
    int ct  = bc % nct;
    int b   = bc / nct;
    int co0 = ct * CO_TILE;
    int pix = blockIdx.x * 256 + threadIdx.x;   // < 15360
    int y   = pix / 480;
    int w   = pix - y * 480;

    const float* ibase = in + (size_t)b * 32 * HW + y * 480 + w;

    bool ym = y > 0, yp = y < 31, wm = w > 0, wp = w < 479;
    int   off[9];
    float msk[9];
    {
        const bool c[9] = { ym && wm, ym, ym && wp,
                            wm,       true, wp,
                            yp && wm, yp, yp && wp };
        const int  o[9] = { -481, -480, -479, -1, 0, 1, 479, 480, 481 };
#pragma unroll
        for (int k = 0; k < 9; ++k) {
            off[k] = c[k] ? o[k] : 0;
            msk[k] = c[k] ? 1.f : 0.f;
        }
    }

    float acc[CO_TILE];
#pragma unroll
    for (int i = 0; i < CO_TILE; ++i) acc[i] = bias ? bias[co0 + i] : 0.f;

    for (int ci = 0; ci < 32; ++ci) {
        const float* ip = ibase + ci * HW;
        float v[9];
#pragma unroll
        for (int k = 0; k < 9; ++k) v[k] = ip[off[k]] * msk[k];

        const float* wrow = wt + ci * 9 * Cout + co0;
#pragma unroll
        for (int k = 0; k < 9; ++k) {
            float xv = v[k];
            const float4* w4p = (const float4*)(wrow + k * Cout);
#pragma unroll
            for (int c = 0; c < CO_TILE / 4; ++c) {
                float4 ww = w4p[c];
                acc[c * 4 + 0] += xv * ww.x;
                acc[c * 4 + 1] += xv * ww.y;
                acc[c * 4 + 2] += xv * ww.z;
                acc[c * 4 + 3] += xv * ww.w;
            }
        }
    }

    size_t obase = (size_t)(b * Cout + co0) * HW + pix;
#pragma unroll
    for (int i = 0; i < CO_TILE; ++i) out[obase + (size_t)i * HW] = acc[i];
}

// ---------------------------------------------------------------------------
// MFMA flash attention, re-tiled for occupancy.
// Grid: 1280 WGs = (b,h,blk) x 4 query-groups; 256 threads (4 waves);
// each wave owns 3 q-tiles of 16 queries (4*4*3*16 = 768 per (b,h,blk)).
// Per 16-key tile: S' = K·Q^T via mfma_16x16x16_f16 (swapped operands so the
// C-frag of S' is directly the A-frag of P), exp2 in-register (cvt_pkrtz),
// P·[V|1|0] via second MFMA; ones-row of V^T gives the denominator free.
// OOB keys: K=V=0, ones=1 -> exp(0)=1 in denom, matches reference padding.
// ---------------------------------------------------------------------------
__global__ __launch_bounds__(256) void attn_mfma(
    const float* __restrict__ qkv, float* __restrict__ att)
{
    __shared__ _Float16 Kl[1280 * 4];      // [j][d] key-major, 8B/key
    __shared__ _Float16 Vl[5 * VSTRIDE];   // [n][j] transposed; row 4 = ones

    int wg    = blockIdx.x;
    int qg    = wg & 3;
    int bhblk = wg >> 2;
    int blk = bhblk % 20;
    int h   = (bhblk / 20) % 8;
    int b   = bhblk / 160;
    int tid  = threadIdx.x;
    int lane = tid & 63;
    int wv   = tid >> 6;     // 0..3

    const float* base = qkv + (size_t)(b * 96 + h * 12) * HW;
    const float* kb = base + 4 * HW;
    const float* vb = base + 8 * HW;

    // stage K (key-major f16) and V^T (+ones row) into LDS
    for (int j = tid; j < 1280; j += 256) {
        int yy = j / 40, wc = j - yy * 40;
        int wpos = blk * 24 + wc - 8;
        float k0 = 0.f, k1 = 0.f, k2 = 0.f, k3 = 0.f;
        float v0 = 0.f, v1 = 0.f, v2 = 0.f, v3 = 0.f;
        if ((unsigned)wpos < 480u) {
            int o = yy * 480 + wpos;
            k0 = kb[o]; k1 = kb[o + HW]; k2 = kb[o + 2 * HW]; k3 = kb[o + 3 * HW];
            v0 = vb[o]; v1 = vb[o + HW]; v2 = vb[o + 2 * HW]; v3 = vb[o + 3 * HW];
        }
        half4 kk = { (_Float16)k0, (_Float16)k1, (_Float16)k2, (_Float16)k3 };
        *(half4*)&Kl[j * 4] = kk;
        Vl[j]               = (_Float16)v0;
        Vl[VSTRIDE + j]     = (_Float16)v1;
        Vl[2 * VSTRIDE + j] = (_Float16)v2;
        Vl[3 * VSTRIDE + j] = (_Float16)v3;
        Vl[4 * VSTRIDE + j] = (_Float16)1.0f;
    }

    // Q B-frags: lane<16 holds query (tile_base+lane)'s 4 dims (pre-scaled)
    const float QS = 0.5f * 1.44269504f;   // dh^-0.5 * log2(e)
    half4 qf[3];
#pragma unroll
    for (int t = 0; t < 3; ++t) {
        half4 qq = { (_Float16)0.f, (_Float16)0.f, (_Float16)0.f, (_Float16)0.f };
        if (lane < 16) {
            int q = qg * 192 + (wv * 3 + t) * 16 + lane;
            int y = q / 24, qc = q - y * 24;
            int o = y * 480 + blk * 24 + qc;
            qq[0] = (_Float16)(base[o] * QS);
            qq[1] = (_Float16)(base[o + HW] * QS);
            qq[2] = (_Float16)(base[o + 2 * HW] * QS);
            qq[3] = (_Float16)(base[o + 3 * HW] * QS);
        }
        qf[t] = qq;
    }

    __syncthreads();

    const half4   hz = { (_Float16)0.f, (_Float16)0.f, (_Float16)0.f, (_Float16)0.f };
    const floatx4 fz = { 0.f, 0.f, 0.f, 0.f };

    floatx4 acc[3];
#pragma unroll
    for (int t = 0; t < 3; ++t) acc[t] = fz;

    int n = lane & 15;          // A-row (key) for ka; B-col (out dim) for vv
    int g = lane >> 4;
    int vn = n > 4 ? 4 : n;

    for (int kt = 0; kt < 80; ++kt) {
        int jb = kt * 16;
        // A-frag of S' = K-tile: lane holds K[jb + n][d=0..3]; lanes>=16 are d>=4 pad
        half4 ka = *(const half4*)&Kl[(jb + n) * 4];
        if (lane >= 16) ka = hz;
        // B-frag of PV = V-tile: lane holds V^T[col=n][jb + g*4 + i]; n==4 -> ones
        half4 vv = *(const half4*)&Vl[vn * VSTRIDE + jb + g * 4];
        if (n > 4) vv = hz;
#pragma unroll
        for (int t = 0; t < 3; ++t) {
            floatx4 s = __builtin_amdgcn_mfma_f32_16x16x16f16(ka, qf[t], fz, 0, 0, 0);
            auto lo = __builtin_amdgcn_cvt_pkrtz(__builtin_amdgcn_exp2f(s[0]),
                                                 __builtin_amdgcn_exp2f(s[1]));
            auto hi = __builtin_amdgcn_cvt_pkrtz(__builtin_amdgcn_exp2f(s[2]),
                                                 __builtin_amdgcn_exp2f(s[3]));
            half4 pa = { (_Float16)lo[0], (_Float16)lo[1],
                         (_Float16)hi[0], (_Float16)hi[1] };
            acc[t] = __builtin_amdgcn_mfma_f32_16x16x16f16(pa, vv, acc[t], 0, 0, 0);
        }
    }

    // epilogue: lane holds O[q = tile+g*4+r][n]; col 4 = softmax denominator
#pragma unroll
    for (int t = 0; t < 3; ++t) {
#pragma unroll
        for (int r = 0; r < 4; ++r) {
            float ls = __shfl(acc[t][r], (lane & 48) + 4);
            if (n < 4) {
                float val = acc[t][r] * __builtin_amdgcn_rcpf(ls);
                int q = qg * 192 + (wv * 3 + t) * 16 + g * 4 + r;
                int y = q / 24, qc = q - y * 24;
                att[((size_t)(b * 32 + h * 4 + n) * 32 + y) * 480 + blk * 24 + qc] = val;
            }
        }
    }
}

extern "C" void kernel_launch(void* const* d_in, const int* in_sizes, int n_in,
                              void* d_out, int out_size, void* d_ws, size_t ws_size,
                              hipStream_t stream) {
    const float* x     = (const float*)d_in[0];
    const float* qkv_w = (const float*)d_in[1];
    const float* qkv_b = (const float*)d_in[2];
    const float* out_w = (const float*)d_in[3];
    float* out = (float*)d_out;

    float* wt1  = (float*)d_ws;                        // 32*9*96  = 27,648 fl
    float* wt2  = wt1 + 32 * 9 * 96;                   // 32*9*32  = 9,216 fl
    float* qkv  = wt2 + 32 * 9 * 32;                   // 2*96*HW  = 2,949,120 fl
    float* att  = qkv + (size_t)2 * 96 * HW;           // 2*32*HW  = 983,040 fl

    // repack weights for coalesced-by-co float4 reads
    repack_w<<<(96 * 288 + 255) / 256, 256, 0, stream>>>(qkv_w, wt1, 96);
    repack_w<<<(32 * 288 + 255) / 256, 256, 0, stream>>>(out_w, wt2, 32);

    // conv1: x -> qkv (2,96,32,480); 16 co per thread
    conv3x3_tiled<16><<<dim3(60, 2 * 6), 256, 0, stream>>>(x, wt1, qkv_b, qkv, 96);

    // attention (MFMA flash, 4 query-groups per (b,h,blk)): qkv -> att
    attn_mfma<<<1280, 256, 0, stream>>>(qkv, att);

    // conv2: att -> out; 8 co per thread
    conv3x3_tiled<8><<<dim3(60, 2 * 4), 256, 0, stream>>>(att, wt2, nullptr, out, 32);
}

// Round 13
// 113.378 us; speedup vs baseline: 4.3360x; 1.0626x over previous
//
#include <hip/hip_runtime.h>
#include <hip/hip_bf16.h>

// x:      (2, 32, 32, 480)  NCHW fp32
// qkv_w:  (96, 32, 3, 3), qkv_b: (96,), out_w: (32, 32, 3, 3)
// D_MODEL=32, N_HEADS=8, dh=4, QUERY_SHAPE=24, MEM_FLANGE=8
// H=32, W=480, nb=20, wlen=40; per (b,h,blk): 768 queries x 1280 keys.

#define HW 15360      // 32*480, one channel plane
#define VSTRIDE 1300  // halves; 650 dwords = 10 mod 32 -> max 2-way bank alias

typedef _Float16 half4 __attribute__((ext_vector_type(4)));
typedef float floatx4 __attribute__((ext_vector_type(4)));

// ---------------------------------------------------------------------------
// Repack weights [Cout][32][3][3] -> [32*9][Cout].
// ---------------------------------------------------------------------------
__global__ __launch_bounds__(256) void repack_w(const float* __restrict__ w,
                                                float* __restrict__ wt, int Cout) {
    int i = blockIdx.x * 256 + threadIdx.x;
    int n = Cout * 288;
    if (i >= n) return;
    int co = i / 288;
    int r  = i - co * 288;            // ci*9 + k
    wt[r * Cout + co] = w[i];
}

// ---------------------------------------------------------------------------
// 3x3 conv, pad 1, NCHW, Cin=32. Each thread: 1 pixel x CO_TILE out-channels.
// Templated on in/out element type (fp32 accumulate always).
// ---------------------------------------------------------------------------
template<int CO_TILE, typename TIN, typename TOUT>
__global__ __launch_bounds__(256) void conv3x3_tiled(
    const TIN* __restrict__ in, const float* __restrict__ wt,
    const float* __restrict__ bias, TOUT* __restrict__ out, int Cout)
{
    int nct = Cout / CO_TILE;
    int bc  = blockIdx.y;
    int ct  = bc % nct;
    int b   = bc / nct;
    int co0 = ct * CO_TILE;
    int pix = blockIdx.x * 256 + threadIdx.x;   // < 15360
    int y   = pix / 480;
    int w   = pix - y * 480;

    const TIN* ibase = in + (size_t)b * 32 * HW + y * 480 + w;

    bool ym = y > 0, yp = y < 31, wm = w > 0, wp = w < 479;
    int   off[9];
    float msk[9];
    {
        const bool c[9] = { ym && wm, ym, ym && wp,
                            wm,       true, wp,
                            yp && wm, yp, yp && wp };
        const int  o[9] = { -481, -480, -479, -1, 0, 1, 479, 480, 481 };
#pragma unroll
        for (int k = 0; k < 9; ++k) {
            off[k] = c[k] ? o[k] : 0;
            msk[k] = c[k] ? 1.f : 0.f;
        }
    }

    float acc[CO_TILE];
#pragma unroll
    for (int i = 0; i < CO_TILE; ++i) acc[i] = bias ? bias[co0 + i] : 0.f;

    for (int ci = 0; ci < 32; ++ci) {
        const TIN* ip = ibase + ci * HW;
        float v[9];
#pragma unroll
        for (int k = 0; k < 9; ++k) v[k] = (float)ip[off[k]] * msk[k];

        const float* wrow = wt + ci * 9 * Cout + co0;
#pragma unroll
        for (int k = 0; k < 9; ++k) {
            float xv = v[k];
            const float4* w4p = (const float4*)(wrow + k * Cout);
#pragma unroll
            for (int c = 0; c < CO_TILE / 4; ++c) {
                float4 ww = w4p[c];
                acc[c * 4 + 0] += xv * ww.x;
                acc[c * 4 + 1] += xv * ww.y;
                acc[c * 4 + 2] += xv * ww.z;
                acc[c * 4 + 3] += xv * ww.w;
            }
        }
    }

    size_t obase = (size_t)(b * Cout + co0) * HW + pix;
#pragma unroll
    for (int i = 0; i < CO_TILE; ++i) out[obase + (size_t)i * HW] = (TOUT)acc[i];
}

// ---------------------------------------------------------------------------
// MFMA flash attention. Grid: 1280 WGs = (b,h,blk) x 4 query-groups, with
// XCD-aware swizzle (orig = (wg&7)*160 + wg>>3) so the 4 groups sharing one
// K/V window (plus neighboring blk windows) land on ONE XCD's L2.
// 256 threads (4 waves), each wave 3 q-tiles of 16 queries.
// Per 16-key tile: S' = K·Q^T via mfma_16x16x16_f16 (swapped operands: C-frag
// of S' == A-frag of P), exp2 in-register, P·[V|1|0] via second MFMA; the
// ones-row of V^T yields the softmax denominator free. Idle fragment lanes
// read a zeroed LDS slot with stride 0 (no per-iter cndmask).
// qkv is f16 (produced by conv1); att written f16 (consumed by conv2).
// ---------------------------------------------------------------------------
__global__ __launch_bounds__(256) void attn_mfma(
    const _Float16* __restrict__ qkv, _Float16* __restrict__ att)
{
    __shared__ _Float16 Kl[1280 * 4];      // [j][d] key-major, 8B/key
    __shared__ _Float16 Vl[5 * VSTRIDE];   // [n][j] transposed; row 4 = ones
    __shared__ _Float16 Zl[8];             // zero slot for idle lanes

    int wg    = blockIdx.x;
    int orig  = (wg & 7) * 160 + (wg >> 3);   // XCD-contiguous remap (bijective)
    int qg    = orig & 3;
    int bhblk = orig >> 2;
    int blk = bhblk % 20;
    int h   = (bhblk / 20) % 8;
    int b   = bhblk / 160;
    int tid  = threadIdx.x;
    int lane = tid & 63;
    int wv   = tid >> 6;     // 0..3

    const _Float16* base = qkv + (size_t)(b * 96 + h * 12) * HW;
    const _Float16* kb = base + 4 * HW;
    const _Float16* vb = base + 8 * HW;

    const _Float16 h0 = (_Float16)0.f;
    if (tid < 2) *(half4*)&Zl[tid * 4] = half4{ h0, h0, h0, h0 };

    // stage K (key-major) and V^T (+ones row) into LDS
    for (int j = tid; j < 1280; j += 256) {
        int yy = j / 40, wc = j - yy * 40;
        int wpos = blk * 24 + wc - 8;
        _Float16 k0 = h0, k1 = h0, k2 = h0, k3 = h0;
        _Float16 v0 = h0, v1 = h0, v2 = h0, v3 = h0;
        if ((unsigned)wpos < 480u) {
            int o = yy * 480 + wpos;
            k0 = kb[o]; k1 = kb[o + HW]; k2 = kb[o + 2 * HW]; k3 = kb[o + 3 * HW];
            v0 = vb[o]; v1 = vb[o + HW]; v2 = vb[o + 2 * HW]; v3 = vb[o + 3 * HW];
        }
        *(half4*)&Kl[j * 4] = half4{ k0, k1, k2, k3 };
        Vl[j]               = v0;
        Vl[VSTRIDE + j]     = v1;
        Vl[2 * VSTRIDE + j] = v2;
        Vl[3 * VSTRIDE + j] = v3;
        Vl[4 * VSTRIDE + j] = (_Float16)1.0f;
    }

    // Q B-frags: lane<16 holds query (tile_base+lane)'s 4 dims (pre-scaled)
    const float QS = 0.5f * 1.44269504f;   // dh^-0.5 * log2(e)
    half4 qf[3];
#pragma unroll
    for (int t = 0; t < 3; ++t) {
        half4 qq = { h0, h0, h0, h0 };
        if (lane < 16) {
            int q = qg * 192 + (wv * 3 + t) * 16 + lane;
            int y = q / 24, qc = q - y * 24;
            int o = y * 480 + blk * 24 + qc;
            qq[0] = (_Float16)((float)base[o] * QS);
            qq[1] = (_Float16)((float)base[o + HW] * QS);
            qq[2] = (_Float16)((float)base[o + 2 * HW] * QS);
            qq[3] = (_Float16)((float)base[o + 3 * HW] * QS);
        }
        qf[t] = qq;
    }

    __syncthreads();

    const floatx4 fz = { 0.f, 0.f, 0.f, 0.f };
    floatx4 acc[3];
#pragma unroll
    for (int t = 0; t < 3; ++t) acc[t] = fz;

    int n = lane & 15;          // A-row (key) for ka; B-col (out dim) for vv
    int g = lane >> 4;

    // stride-0 zero-slot pointers for idle lanes (replaces per-iter cndmask)
    const _Float16* kap = (lane < 16) ? &Kl[n * 4] : Zl;
    int kstep = (lane < 16) ? 64 : 0;              // 16 keys * 4 halves
    const _Float16* vap = (n <= 4) ? &Vl[n * VSTRIDE + g * 4] : Zl;
    int vstep = (n <= 4) ? 16 : 0;                 // 16 halves

    for (int kt = 0; kt < 80; ++kt) {
        half4 ka = *(const half4*)kap; kap += kstep;
        half4 vv = *(const half4*)vap; vap += vstep;
#pragma unroll
        for (int t = 0; t < 3; ++t) {
            floatx4 s = __builtin_amdgcn_mfma_f32_16x16x16f16(ka, qf[t], fz, 0, 0, 0);
            auto lo = __builtin_amdgcn_cvt_pkrtz(__builtin_amdgcn_exp2f(s[0]),
                                                 __builtin_amdgcn_exp2f(s[1]));
            auto hi = __builtin_amdgcn_cvt_pkrtz(__builtin_amdgcn_exp2f(s[2]),
                                                 __builtin_amdgcn_exp2f(s[3]));
            half4 pa = { (_Float16)lo[0], (_Float16)lo[1],
                         (_Float16)hi[0], (_Float16)hi[1] };
            acc[t] = __builtin_amdgcn_mfma_f32_16x16x16f16(pa, vv, acc[t], 0, 0, 0);
        }
    }

    // epilogue: lane holds O[q = tile+g*4+r][n]; col 4 = softmax denominator
#pragma unroll
    for (int t = 0; t < 3; ++t) {
#pragma unroll
        for (int r = 0; r < 4; ++r) {
            float ls = __shfl(acc[t][r], (lane & 48) + 4);
            if (n < 4) {
                float val = acc[t][r] * __builtin_amdgcn_rcpf(ls);
                int q = qg * 192 + (wv * 3 + t) * 16 + g * 4 + r;
                int y = q / 24, qc = q - y * 24;
                att[((size_t)(b * 32 + h * 4 + n) * 32 + y) * 480 + blk * 24 + qc] =
                    (_Float16)val;
            }
        }
    }
}

extern "C" void kernel_launch(void* const* d_in, const int* in_sizes, int n_in,
                              void* d_out, int out_size, void* d_ws, size_t ws_size,
                              hipStream_t stream) {
    const float* x     = (const float*)d_in[0];
    const float* qkv_w = (const float*)d_in[1];
    const float* qkv_b = (const float*)d_in[2];
    const float* out_w = (const float*)d_in[3];
    float* out = (float*)d_out;

    float* wt1 = (float*)d_ws;                          // 32*9*96 = 27,648 fl
    float* wt2 = wt1 + 32 * 9 * 96;                     // 32*9*32 = 9,216 fl
    _Float16* qkv16 = (_Float16*)(wt2 + 32 * 9 * 32);   // 2*96*HW halves (5.9 MB)
    _Float16* att16 = qkv16 + (size_t)2 * 96 * HW;      // 2*32*HW halves (1.9 MB)

    // repack weights for coalesced-by-co float4 reads
    repack_w<<<(96 * 288 + 255) / 256, 256, 0, stream>>>(qkv_w, wt1, 96);
    repack_w<<<(32 * 288 + 255) / 256, 256, 0, stream>>>(out_w, wt2, 32);

    // conv1: x (fp32) -> qkv16 (f16, 2,96,32,480); 16 co per thread
    conv3x3_tiled<16, float, _Float16>
        <<<dim3(60, 2 * 6), 256, 0, stream>>>(x, wt1, qkv_b, qkv16, 96);

    // attention (MFMA flash, XCD-swizzled): qkv16 -> att16
    attn_mfma<<<1280, 256, 0, stream>>>(qkv16, att16);

    // conv2: att16 (f16) -> out (fp32); 8 co per thread
    conv3x3_tiled<8, _Float16, float>
        <<<dim3(60, 2 * 4), 256, 0, stream>>>(att16, wt2, nullptr, out, 32);
}